// Round 11
// baseline (401.871 us; speedup 1.0000x reference)
//
#include <hip/hip_runtime.h>
#include <math.h>

#define BS   8
#define CIN  512
#define HC_  64
#define C2   256
#define NPIX 4096
#define WAO  384
#define TK   32           // KV tile size in k_attn
#define NT   (NPIX / TK)  // 128 KV steps

typedef __attribute__((ext_vector_type(8))) short short8;
typedef __attribute__((ext_vector_type(4))) float f32x4;

__device__ __forceinline__ ushort f2bf(float f) {
    union { float f; unsigned int u; } v; v.f = f;
    return (ushort)((v.u + 0x7FFFu + ((v.u >> 16) & 1u)) >> 16);
}

#define MFMA16(a, b, c) __builtin_amdgcn_mfma_f32_16x16x32_bf16((a), (b), (c), 0, 0, 0)

// async global->LDS, 16B per lane; LDS dest = base + lane*16 (wave-uniform base)
__device__ __forceinline__ void gl_lds16(const ushort* g, ushort* l) {
    __builtin_amdgcn_global_load_lds(
        (const __attribute__((address_space(1))) unsigned int*)g,
        (__attribute__((address_space(3))) unsigned int*)l, 16, 0, 0);
}

// ---------------------------------------------------------------------------
// Kernel W: convert Wa (384x512) and Wo (512x256) fp32 -> bf16 once.
// ---------------------------------------------------------------------------
__global__ __launch_bounds__(256) void k_cvt_w(
    const float* __restrict__ Wa, const float* __restrict__ Wo,
    ushort* __restrict__ wab, ushort* __restrict__ wob)
{
    const int i = (blockIdx.x * 256 + threadIdx.x) * 4;
    const int na = WAO * CIN;
    if (i < na) {
        const float4 v = *(const float4*)&Wa[i];
        ushort4 o; o.x = f2bf(v.x); o.y = f2bf(v.y); o.z = f2bf(v.z); o.w = f2bf(v.w);
        *(ushort4*)&wab[i] = o;
    } else {
        const int j = i - na;
        if (j < CIN * C2) {
            const float4 v = *(const float4*)&Wo[j];
            ushort4 o; o.x = f2bf(v.x); o.y = f2bf(v.y); o.z = f2bf(v.z); o.w = f2bf(v.w);
            *(ushort4*)&wob[j] = o;
        }
    }
}

// ---------------------------------------------------------------------------
// Kernel A: w = Wa @ inputs, MFMA bf16. The full [512c][64px] input tile is
// staged in LDS ONCE (66.5 KB bf16), then 3 o-passes x 16 k-steps with acc[8]
// (registers stay low; fp32 input read from HBM exactly once: 402->134 MB).
// Writes qt[b][n][64], kt[b][m][64] (transposed), vb[b][c][m] (natural).
// grid (64 n-tiles, 8 batch), block 256 (4 waves x 16 n).
// ---------------------------------------------------------------------------
__global__ __launch_bounds__(256) void k_proj_a(
    const float* __restrict__ inp, const ushort* __restrict__ wab,
    ushort* __restrict__ qt, ushort* __restrict__ kt, ushort* __restrict__ vb)
{
    __shared__ __align__(16) ushort it[64][520];   // [n][c], pad 8 (stride 1040B)
    const int b  = blockIdx.y;
    const int n0 = blockIdx.x * 64;
    const int t    = threadIdx.x;
    const int wave = t >> 6, lane = t & 63;
    const int ln   = lane & 15, gr = lane >> 4;
    const int wn   = wave * 16;

    // stage whole tile: 512 ch x 16 float4 pixel-groups = 8192 float4s.
#pragma unroll 4
    for (int i = 0; i < 32; ++i) {
        const int flat = i * 256 + t;
        const int px  = (flat & 15) * 4;
        const int c   = flat >> 4;
        const float4 v = *(const float4*)&inp[((size_t)b * CIN + c) * NPIX + n0 + px];
        it[px + 0][c] = f2bf(v.x); it[px + 1][c] = f2bf(v.y);
        it[px + 2][c] = f2bf(v.z); it[px + 3][c] = f2bf(v.w);
    }
    __syncthreads();

    const int n = n0 + wn + ln;
    for (int op = 0; op < 3; ++op) {
        f32x4 acc[8];
#pragma unroll
        for (int i = 0; i < 8; ++i) acc[i] = (f32x4){0.f, 0.f, 0.f, 0.f};
        for (int ks = 0; ks < 16; ++ks) {
            const int c0 = ks * 32;
            const short8 bf = *(const short8*)&it[wn + ln][c0 + gr * 8];
#pragma unroll
            for (int ot = 0; ot < 8; ++ot) {
                const int row = op * 128 + ot * 16 + ln;
                const short8 af = *(const short8*)&wab[(size_t)row * CIN + c0 + gr * 8];
                acc[ot] = MFMA16(af, bf, acc[ot]);
            }
        }
        if (op == 0) {
#pragma unroll
            for (int ot = 0; ot < 8; ++ot) {
                const ushort b0 = f2bf(acc[ot][0]), b1 = f2bf(acc[ot][1]);
                const ushort b2 = f2bf(acc[ot][2]), b3 = f2bf(acc[ot][3]);
                uint2 pk;
                pk.x = (unsigned int)b0 | ((unsigned int)b1 << 16);
                pk.y = (unsigned int)b2 | ((unsigned int)b3 << 16);
                ushort* base = (ot < 4) ? qt : kt;
                const int c4 = (ot & 3) * 16 + 4 * gr;
                *(uint2*)&base[((size_t)b * NPIX + n) * 64 + c4] = pk;
            }
        } else {
#pragma unroll
            for (int ot = 0; ot < 8; ++ot) {
                const int cb = (op - 1) * 128 + ot * 16 + 4 * gr;
#pragma unroll
                for (int r = 0; r < 4; ++r)
                    vb[((size_t)b * C2 + cb + r) * NPIX + n] = f2bf(acc[ot][r]);
            }
        }
    }
}

// ---------------------------------------------------------------------------
// Kernel B: flash attention (r4 structure, 174us reference) + shuffle-light
// softmax: row-sum kept as per-lane partial (reduced once in epilogue);
// cross-lane max reduce only inside the rare defer-max branch.
// 4 waves x 16 q-rows, TK=32, K/V ring-3 via global_load_lds, both-sides XOR
// swizzles, end-of-step s_waitcnt vmcnt(4) (never 0 in steady state),
// raw s_barrier, setprio around PV. grid 512, b = bid&7 (one batch/XCD L2).
// LDS: K 12K + V 48K + P 5K = 65 KB -> 2 blocks/CU.
// ---------------------------------------------------------------------------
__global__ __launch_bounds__(256, 2) void k_attn(
    const ushort* __restrict__ qt, const ushort* __restrict__ kt,
    const ushort* __restrict__ vb, ushort* __restrict__ yt)
{
    __shared__ __align__(16) ushort ks[3][TK][64];    // [m][c], slot ^= (m&7)
    __shared__ __align__(16) ushort vs[3][C2][TK];    // [c][m], slot ^= ((c>>1)&3)
    __shared__ __align__(16) ushort ps[4][16][40];    // per-wave P [n][m]

    const int bid = blockIdx.x;
    const int b   = bid & 7;
    const int n0  = (bid >> 3) * 64;
    const int t    = threadIdx.x;
    const int wave = t >> 6, lane = t & 63;
    const int ln   = lane & 15, gr = lane >> 4;

    const ushort* ktb = kt + (size_t)b * NPIX * 64;
    const ushort* vbb = vb + (size_t)b * C2 * NPIX;

    const int qrow = n0 + wave * 16 + ln;
    const short8 qf0 = *(const short8*)&qt[((size_t)b * NPIX + qrow) * 64 + gr * 8];
    const short8 qf1 = *(const short8*)&qt[((size_t)b * NPIX + qrow) * 64 + 32 + gr * 8];
    asm volatile("s_waitcnt vmcnt(0)" ::: "memory");   // exact vmcnt accounting
    __builtin_amdgcn_sched_barrier(0);

    // swizzled read offsets (ushort units)
    const int ksl0 = ((gr ^ (ln & 7)) << 3);
    const int ksl1 = (((4 + gr) ^ (ln & 7)) << 3);
    const int vsl  = ((gr ^ ((ln >> 1) & 3)) << 3);
    // staging lane roles (source pre-swizzled; LDS dest linear)
    const int krow = lane >> 3, kslot = (lane & 7) ^ krow;              // 8 m-rows
    const int vrow = lane >> 2, vslot = (lane & 3) ^ ((vrow >> 1) & 3); // 16 c-rows

    // K issued FIRST, then 4x V: end-of-body vmcnt(4) = counted drain.
    auto stage = [&](int buf, int tile) {
        const int m0 = tile * TK;
        gl_lds16(&ktb[(size_t)(m0 + 8 * wave + krow) * 64 + kslot * 8],
                 &ks[buf][8 * wave][0]);
#pragma unroll
        for (int jj = 0; jj < 4; ++jj) {
            const int j = 4 * wave + jj;
            gl_lds16(&vbb[(size_t)(j * 16 + vrow) * NPIX + m0 + vslot * 8],
                     &vs[buf][j * 16][0]);
        }
    };

    f32x4 yacc[16];
#pragma unroll
    for (int i = 0; i < 16; ++i) yacc[i] = (f32x4){0.f, 0.f, 0.f, 0.f};
    float mrun = -INFINITY, lrun = 0.f;    // lrun: per-lane partial row sum
    const f32x4 zero = {0.f, 0.f, 0.f, 0.f};

    stage(0, 0);
    stage(1, 1);
    asm volatile("s_waitcnt vmcnt(5)" ::: "memory");
    __builtin_amdgcn_s_barrier();
    __builtin_amdgcn_sched_barrier(0);

    int cur = 0;
    for (int tt = 0; tt < NT; ++tt) {
        if (tt + 2 < NT) { int pre = cur + 2; if (pre >= 3) pre -= 3; stage(pre, tt + 2); }

        // ---- S^T = K Q : lane (gr,ln) holds S[m = mt*16+4gr+r][q-row ln] ----
        f32x4 s[2];
#pragma unroll
        for (int mt = 0; mt < 2; ++mt) {
            const ushort* kp = &ks[cur][mt * 16 + ln][0];
            const short8 kf0 = *(const short8*)(kp + ksl0);
            const short8 kf1 = *(const short8*)(kp + ksl1);
            s[mt] = MFMA16(kf1, qf1, MFMA16(kf0, qf0, zero));
        }
        // ---- online softmax, defer-max THR=8, shuffle-light ----
        const float tm = fmaxf(fmaxf(fmaxf(s[0][0], s[0][1]), fmaxf(s[0][2], s[0][3])),
                               fmaxf(fmaxf(s[1][0], s[1][1]), fmaxf(s[1][2], s[1][3])));
        if (__any(tm > mrun + 8.f)) {
            float tr = fmaxf(tm, __shfl_xor(tm, 16));
            tr = fmaxf(tr, __shfl_xor(tr, 32));
            const float mnew = fmaxf(mrun, tr);      // row-uniform
            const float rsc  = __expf(mrun - mnew);
            mrun = mnew;
            lrun *= rsc;
            const float r0 = __shfl(rsc, 4 * gr + 0);
            const float r1 = __shfl(rsc, 4 * gr + 1);
            const float r2 = __shfl(rsc, 4 * gr + 2);
            const float r3 = __shfl(rsc, 4 * gr + 3);
#pragma unroll
            for (int ct = 0; ct < 16; ++ct) {
                yacc[ct][0] *= r0; yacc[ct][1] *= r1;
                yacc[ct][2] *= r2; yacc[ct][3] *= r3;
            }
        }
        const float p0 = __expf(s[0][0] - mrun), p1 = __expf(s[0][1] - mrun);
        const float p2 = __expf(s[0][2] - mrun), p3 = __expf(s[0][3] - mrun);
        const float p4 = __expf(s[1][0] - mrun), p5 = __expf(s[1][1] - mrun);
        const float p6 = __expf(s[1][2] - mrun), p7 = __expf(s[1][3] - mrun);
        uint2 w0, w1;
        w0.x = (unsigned int)f2bf(p0) | ((unsigned int)f2bf(p1) << 16);
        w0.y = (unsigned int)f2bf(p2) | ((unsigned int)f2bf(p3) << 16);
        w1.x = (unsigned int)f2bf(p4) | ((unsigned int)f2bf(p5) << 16);
        w1.y = (unsigned int)f2bf(p6) | ((unsigned int)f2bf(p7) << 16);
        *(uint2*)&ps[wave][ln][4 * gr]      = w0;
        *(uint2*)&ps[wave][ln][16 + 4 * gr] = w1;
        lrun += (p0 + p1) + (p2 + p3) + ((p4 + p5) + (p6 + p7));   // partial

        asm volatile("s_waitcnt lgkmcnt(0)" ::: "memory");   // P writes visible
        __builtin_amdgcn_sched_barrier(0);
        const short8 pf = *(const short8*)&ps[wave][ln][gr * 8];
        // ---- Y += P V^T  (16 n x 256 c per wave) ----
        const ushort* vbase = &vs[cur][0][0];
        __builtin_amdgcn_s_setprio(1);
#pragma unroll
        for (int ct = 0; ct < 16; ++ct) {
            const short8 vf = *(const short8*)(vbase + (ct * 16 + ln) * TK + vsl);
            yacc[ct] = MFMA16(pf, vf, yacc[ct]);
        }
        __builtin_amdgcn_s_setprio(0);
        __builtin_amdgcn_sched_barrier(0);
        if (tt + 1 < NT) {
            if (tt + 2 < NT) { asm volatile("s_waitcnt vmcnt(4)" ::: "memory"); }
            else             { asm volatile("s_waitcnt vmcnt(0)" ::: "memory"); }
            __builtin_amdgcn_s_barrier();
            __builtin_amdgcn_sched_barrier(0);
        }
        cur = cur + 1; if (cur >= 3) cur -= 3;
    }

    // ---- epilogue: reduce per-lane partial row sums, normalize, write yt ----
    lrun += __shfl_xor(lrun, 16);
    lrun += __shfl_xor(lrun, 32);          // full row sum for q-row ln
    const float il0 = 1.f / __shfl(lrun, 4 * gr + 0);
    const float il1 = 1.f / __shfl(lrun, 4 * gr + 1);
    const float il2 = 1.f / __shfl(lrun, 4 * gr + 2);
    const float il3 = 1.f / __shfl(lrun, 4 * gr + 3);
#pragma unroll
    for (int ct = 0; ct < 16; ++ct) {
        const int c = ct * 16 + ln;
        const int nb = n0 + wave * 16 + 4 * gr;
        yt[((size_t)b * NPIX + nb + 0) * C2 + c] = f2bf(yacc[ct][0] * il0);
        yt[((size_t)b * NPIX + nb + 1) * C2 + c] = f2bf(yacc[ct][1] * il1);
        yt[((size_t)b * NPIX + nb + 2) * C2 + c] = f2bf(yacc[ct][2] * il2);
        yt[((size_t)b * NPIX + nb + 3) * C2 + c] = f2bf(yacc[ct][3] * il3);
    }
}

// ---------------------------------------------------------------------------
// Kernel C: out = gamma * (Wo @ y) + inputs, MFMA bf16, no LDS.
// 2-way j-fusion (acc[16], 256 rows per block): yt HBM reads halved.
// grid (64 n-tiles, 2 j-tiles, 8 batch), block 256 (4 waves x 16 n).
// ---------------------------------------------------------------------------
__global__ __launch_bounds__(256) void k_proj_o(
    const ushort* __restrict__ yt, const ushort* __restrict__ wob,
    const float* __restrict__ inp, const float* __restrict__ gamma,
    float* __restrict__ out)
{
    const int b  = blockIdx.z;
    const int j0 = blockIdx.y * 256;
    const int n0 = blockIdx.x * 64;
    const int t    = threadIdx.x;
    const int wave = t >> 6, lane = t & 63;
    const int ln   = lane & 15, gr = lane >> 4;
    const int n = n0 + wave * 16 + ln;

    f32x4 acc[16];
#pragma unroll
    for (int i = 0; i < 16; ++i) acc[i] = (f32x4){0.f, 0.f, 0.f, 0.f};

#pragma unroll
    for (int ksi = 0; ksi < 8; ++ksi) {
        const int c0 = ksi * 32;
        const short8 bf = *(const short8*)&yt[((size_t)b * NPIX + n) * C2 + c0 + gr * 8];
#pragma unroll
        for (int jt = 0; jt < 16; ++jt) {
            const int row = j0 + jt * 16 + ln;
            const short8 af = *(const short8*)&wob[(size_t)row * C2 + c0 + gr * 8];
            acc[jt] = MFMA16(af, bf, acc[jt]);
        }
    }
    const float g = gamma[0];
#pragma unroll
    for (int jt = 0; jt < 16; ++jt) {
#pragma unroll
        for (int r = 0; r < 4; ++r) {
            const int j = j0 + jt * 16 + 4 * gr + r;
            const size_t idx = ((size_t)b * CIN + j) * NPIX + n;
            out[idx] = fmaf(g, acc[jt][r], inp[idx]);
        }
    }
}

extern "C" void kernel_launch(void* const* d_in, const int* in_sizes, int n_in,
                              void* d_out, int out_size, void* d_ws, size_t ws_size,
                              hipStream_t stream) {
    const float* inputs = (const float*)d_in[0];
    const float* Wa     = (const float*)d_in[1];
    const float* Wo     = (const float*)d_in[2];
    const float* gamma  = (const float*)d_in[3];
    float* out = (float*)d_out;

    const size_t qt_e  = (size_t)BS * NPIX * 64;
    const size_t kt_e  = (size_t)BS * NPIX * 64;
    const size_t vb_e  = (size_t)BS * C2 * NPIX;
    const size_t yt_e  = (size_t)BS * NPIX * C2;
    const size_t wab_e = (size_t)WAO * CIN;
    const size_t wob_e = (size_t)CIN * C2;

    ushort *qt, *kt, *vb, *yt, *wab, *wob;
    if (ws_size >= (qt_e + kt_e + vb_e + yt_e + wab_e + wob_e) * sizeof(ushort)) {
        qt  = (ushort*)d_ws;
        kt  = qt + qt_e;
        vb  = kt + kt_e;
        yt  = vb + vb_e;
        wab = yt + yt_e;
        wob = wab + wab_e;
    } else {
        // vb lives in d_out (16 MB of the 64 MB fp32 out buffer; fully consumed
        // by k_attn before k_proj_o writes out). Rest (~25 MB) in d_ws.
        vb  = (ushort*)d_out;
        qt  = (ushort*)d_ws;
        kt  = qt + qt_e;
        yt  = kt + kt_e;
        wab = yt + yt_e;
        wob = wab + wab_e;
    }

    k_cvt_w <<<dim3(320),      256, 0, stream>>>(Wa, Wo, wab, wob);
    k_proj_a<<<dim3(64, 8),    256, 0, stream>>>(inputs, wab, qt, kt, vb);
    k_attn  <<<dim3(512),      256, 0, stream>>>(qt, kt, vb, yt);
    k_proj_o<<<dim3(64, 2, 8), 256, 0, stream>>>(yt, wob, inputs, gamma, out);
}